// Round 6
// baseline (248.801 us; speedup 1.0000x reference)
//
#include <hip/hip_runtime.h>

constexpr int Tt = 384;   // timesteps
constexpr int Cc = 96;    // classes (blank = 95)
constexpr int Ll = 48;    // max label length
constexpr int Gg = 8;     // rows per group (= rescale period)
constexpr int NG = 24;    // groups per half (24*8 = 192)

#define L2E 1.4426950408889634f
#define LN2 0.6931471805599453f
#define LNEG (-3.0e38f)

// ---- DPP helpers (VALU pipe) ----
template <int CTRL, int RM = 0xF>
__device__ __forceinline__ float dppf(float x) {
    return __int_as_float(
        __builtin_amdgcn_update_dpp(0, __float_as_int(x), CTRL, RM, 0xF, true));
}
template <int CTRL>
__device__ __forceinline__ int dppi(int x) {
    return __builtin_amdgcn_update_dpp(0, x, CTRL, 0xF, 0xF, true);
}
__device__ __forceinline__ float bcast63(float x) {
    return __int_as_float(__builtin_amdgcn_readlane(__float_as_int(x), 63));
}
// full-wave sum of non-negative values, result broadcast
__device__ __forceinline__ float wsum(float x) {
    x += dppf<0x111>(x);          // row_shr:1
    x += dppf<0x112>(x);          // row_shr:2
    x += dppf<0x114>(x);          // row_shr:4
    x += dppf<0x118>(x);          // row_shr:8
    x += dppf<0x142, 0xA>(x);     // row_bcast:15 -> rows 1,3
    x += dppf<0x143, 0xC>(x);     // row_bcast:31 -> rows 2,3
    return bcast63(x);
}
__device__ __forceinline__ float shup1(float x) { return dppf<0x138>(x); } // lane i <- i-1, 0 into lane 0
__device__ __forceinline__ float shdn1(float x) { return dppf<0x130>(x); } // lane i <- i+1, 0 into lane 63
__device__ __forceinline__ float exp2i(int d) {  // 2^d, clamped to fp32-normal range
    d = d < -126 ? -126 : (d > 126 ? 126 : d);
    return __int_as_float((d + 127) << 23);
}

// ==== kernel 1: Zs[b] = sum_t log2(sum_c exp(logit[b][t][c])) ====
// 8 waves/block, wave w reduces rows [48w, 48w+48). Full-occupancy streaming.
// f64 accumulation + fixed-order combine -> deterministic.
__global__ __launch_bounds__(512) void ctc_zsum(const float* __restrict__ pred,
                                                float* __restrict__ zs,
                                                float* __restrict__ out) {
    const int b    = blockIdx.x;
    const int lane = threadIdx.x & 63;
    const int wv   = threadIdx.x >> 6;
    const float2* rp2 = (const float2*)(pred + (size_t)b * Tt * Cc);
    __shared__ double part[8];

    if (b == 0 && threadIdx.x == 0) out[0] = 0.0f;   // dp launches after zsum completes

    const int t0 = wv * 48;
    double acc = 0.0;
    float2 qa = (lane < 48) ? rp2[(size_t)t0 * 48 + lane] : make_float2(-1e4f, -1e4f);
    for (int j = 0; j < 48; ++j) {
        float2 qn = qa;
        if (j + 1 < 48)
            qn = (lane < 48) ? rp2[(size_t)(t0 + j + 1) * 48 + lane]
                             : make_float2(-1e4f, -1e4f);
        float ex = __builtin_amdgcn_exp2f(qa.x * L2E);   // lanes>=48 -> 0
        float ey = __builtin_amdgcn_exp2f(qa.y * L2E);
        float z  = wsum(ex + ey);
        acc += (double)__log2f(z);
        qa = qn;
    }
    if (lane == 0) part[wv] = acc;
    __syncthreads();
    if (threadIdx.x == 0) {
        double s = 0.0;
#pragma unroll
        for (int w = 0; w < 8; ++w) s += part[w];
        zs[b] = (float)s;
    }
}

// ==== kernel 2: forward/backward DP on UNNORMALIZED emissions ====

// gather loads for one 8-row group: lane i reads logit[t][label_i] and logit[t][95]
template <bool FWD>
__device__ __forceinline__ void dp_load(const float* __restrict__ rp, float* ql,
                                        float* qb, int g, int labv) {
#pragma unroll
    for (int j = 0; j < Gg; ++j) {
        int k = g * Gg + j;
        int t = FWD ? k : (Tt - 1 - k);
        ql[j] = rp[t * Cc + labv];    // per-lane gather within the 384-B row
        qb[j] = rp[t * Cc + 95];      // uniform address -> single-line broadcast
    }
}

// one 8-step DP group on raw logits (emission = exp2(logit*L2E), unnormalized)
template <bool FWD>
__device__ __forceinline__ void dp_group(const float* ql, const float* qb,
                                         float allow2f, float& st_e, float& st_o,
                                         int& ls, float& f, float& a2f) {
    float el[Gg], eb[Gg];
#pragma unroll
    for (int j = 0; j < Gg; ++j) {
        el[j] = __builtin_amdgcn_exp2f(ql[j] * L2E);
        eb[j] = __builtin_amdgcn_exp2f(qb[j] * L2E);
    }
#pragma unroll
    for (int j = 0; j < Gg; ++j) {
        if (FWD) {
            float sh = shup1(st_o);                      // alpha(2i-1), lane i-1 scale
            float t0 = st_e + st_o;
            float ne = fmaf(f, sh, st_e) * eb[j];
            float no = fmaf(a2f, sh, t0) * el[j];
            st_e = ne; st_o = no;
        } else {
            float en = shdn1(st_e);                      // beta(2i+2)
            float on = shdn1(st_o);                      // beta(2i+3)
            float ne = (st_e + st_o) * eb[j];
            float no = fmaf(a2f, on, fmaf(f, en, st_o)) * el[j];
            st_e = ne; st_o = no;
        }
    }
    // per-lane exact power-of-2 rescale (handles unnormalized dynamic range;
    // inter-lane exponent differences are unchanged since Z_t is a common factor)
    float m = fmaxf(st_e, st_o);
    bool z  = (m == 0.0f);
    int eb2 = (__float_as_int(m) >> 23) & 0xFF;
    eb2 = eb2 > 253 ? 253 : eb2;
    float r = z ? 1.0f : __int_as_float((254 - eb2) << 23);   // 2^(127-eb2), exact
    st_e *= r; st_o *= r;
    ls += z ? 0 : (eb2 - 127);
    // exponent adoption for zero lanes (front moves <= 8 lanes/group)
#pragma unroll
    for (int it = 0; it < 8; ++it) {
        int lsn = FWD ? dppi<0x138>(ls) : dppi<0x130>(ls);
        ls = z ? lsn : ls;
    }
    int lsn2 = FWD ? dppi<0x138>(ls) : dppi<0x130>(ls);
    f   = exp2i(lsn2 - ls);
    a2f = allow2f * f;
}

// self-contained half: loads 4 groups ahead (~3 group bodies of issue distance)
template <bool FWD>
__device__ __forceinline__ void run_half(const float* __restrict__ rp, int labv,
                                         float allow2f, float& st_e, float& st_o,
                                         int& ls, float& f, float& a2f) {
    float qlA[Gg], qbA[Gg], qlB[Gg], qbB[Gg], qlC[Gg], qbC[Gg], qlD[Gg], qbD[Gg];
    dp_load<FWD>(rp, qlA, qbA, 0, labv);
    dp_load<FWD>(rp, qlB, qbB, 1, labv);
    dp_load<FWD>(rp, qlC, qbC, 2, labv);
    dp_load<FWD>(rp, qlD, qbD, 3, labv);
    for (int g4 = 0; g4 < 5; ++g4) {      // groups 0..19; loads reach exactly 23
        int gb = g4 * 4;
        dp_group<FWD>(qlA, qbA, allow2f, st_e, st_o, ls, f, a2f);
        dp_load<FWD>(rp, qlA, qbA, gb + 4, labv);
        dp_group<FWD>(qlB, qbB, allow2f, st_e, st_o, ls, f, a2f);
        dp_load<FWD>(rp, qlB, qbB, gb + 5, labv);
        dp_group<FWD>(qlC, qbC, allow2f, st_e, st_o, ls, f, a2f);
        dp_load<FWD>(rp, qlC, qbC, gb + 6, labv);
        dp_group<FWD>(qlD, qbD, allow2f, st_e, st_o, ls, f, a2f);
        dp_load<FWD>(rp, qlD, qbD, gb + 7, labv);
    }
    dp_group<FWD>(qlA, qbA, allow2f, st_e, st_o, ls, f, a2f);   // 20
    dp_group<FWD>(qlB, qbB, allow2f, st_e, st_o, ls, f, a2f);   // 21
    dp_group<FWD>(qlC, qbC, allow2f, st_e, st_o, ls, f, a2f);   // 22
    dp_group<FWD>(qlD, qbD, allow2f, st_e, st_o, ls, f, a2f);   // 23
}

// 2 waves/block: wv0 = fwd half (t=0..191), wv1 = bwd half (t=383..192).
__global__ __launch_bounds__(128) void ctc_dp(const int* __restrict__ labels,
                                              const float* __restrict__ pred,
                                              const float* __restrict__ zs,
                                              float* __restrict__ out,
                                              float invB) {
    const int b    = blockIdx.x;
    const int lane = threadIdx.x & 63;
    const int wv   = threadIdx.x >> 6;
    const float* rp = pred + (size_t)b * Tt * Cc;

    __shared__ float sbe[64], sbo[64];
    __shared__ int   slsb[64];

    float zsb = zs[b];   // written by ctc_zsum (prior kernel on same stream)

    // lane i holds label i
    int v = (lane < Ll) ? labels[(size_t)b * Ll + lane] : -1;
    int present = (lane < Ll) && (v != -1);
    int labv = (v < 0) ? 0 : v;
    unsigned long long pm = __ballot(present);
    int len = __popcll(pm);
    int lab_p = __shfl(labv, (lane - 1) & 63, 64);
    int lab_n = __shfl(labv, (lane + 1) & 63, 64);

    float st_e, st_o = 0.0f, f = 1.0f, a2f, allow2f;
    int   ls = 0;

    if (wv == 0) {            // fwd DP: virtual pre-start state at lane 0
        allow2f = (lane >= 1 && labv != lab_p) ? 1.0f : 0.0f;
        st_e = (lane == 0) ? 1.0f : 0.0f;
        a2f = allow2f;
        run_half<true>(rp, labv, allow2f, st_e, st_o, ls, f, a2f);
    } else {                  // bwd DP: virtual post-end state at lane == len
        allow2f = (labv != lab_n) ? 1.0f : 0.0f;
        st_e = (lane == len) ? 1.0f : 0.0f;
        a2f = allow2f;
        run_half<false>(rp, labv, allow2f, st_e, st_o, ls, f, a2f);
        sbe[lane]  = st_e;
        sbo[lane]  = st_o;
        slsb[lane] = ls;
    }
    __syncthreads();

    if (wv == 0) {
        // transition half-step (no emission) to meet beta at t = 192
        float sh  = shup1(st_o);
        int   lsu = dppi<0x138>(ls);
        float fup = exp2i(lsu - ls);
        float Ae = fmaf(fup, sh, st_e);
        float Ao = fmaf(allow2f * fup, sh, st_e + st_o);
        // combine in log2 domain with integer exponents restored
        float be = sbe[lane], bo = sbo[lane];
        float base = (float)(ls + slsb[lane]);
        float l1 = (Ae > 0.0f && be > 0.0f) ? __log2f(Ae) + __log2f(be) + base : LNEG;
        float l2 = (Ao > 0.0f && bo > 0.0f) ? __log2f(Ao) + __log2f(bo) + base : LNEG;
        float mm = fmaxf(l1, l2);
#pragma unroll
        for (int off = 32; off >= 1; off >>= 1) mm = fmaxf(mm, __shfl_xor(mm, off, 64));
        float ss = exp2f(l1 - mm) + exp2f(l2 - mm);
#pragma unroll
        for (int off = 32; off >= 1; off >>= 1) ss += __shfl_xor(ss, off, 64);
        if (lane == 0) {
            // subtract the factored-out log2(prod_t Z_t)
            float ll = (mm + __log2f(ss) - zsb) * LN2;
            atomicAdd(out, -ll * invB);
        }
    }
}

extern "C" void kernel_launch(void* const* d_in, const int* in_sizes, int n_in,
                              void* d_out, int out_size, void* d_ws, size_t ws_size,
                              hipStream_t stream) {
    const int*   labels = (const int*)d_in[0];
    const float* pred   = (const float*)d_in[1];
    float*       out    = (float*)d_out;
    float*       zs     = (float*)d_ws;    // 1024 floats = 4 KB

    const int B = in_sizes[0] / Ll;  // 1024

    hipLaunchKernelGGL(ctc_zsum, dim3(B), dim3(512), 0, stream, pred, zs, out);
    hipLaunchKernelGGL(ctc_dp, dim3(B), dim3(128), 0, stream,
                       labels, pred, zs, out, 1.0f / (float)B);
}

// Round 7
// 221.588 us; speedup vs baseline: 1.1228x; 1.1228x over previous
//
#include <hip/hip_runtime.h>

constexpr int Tt = 384;   // timesteps
constexpr int Cc = 96;    // classes (blank = 95)
constexpr int Ll = 48;    // max label length
constexpr int Gg = 8;     // rows per group (= rescale period)
constexpr int NG = 24;    // groups per half (24*8 = 192)

#define L2E 1.4426950408889634f
#define LN2 0.6931471805599453f
#define LNEG (-3.0e38f)

// ---- DPP helpers (VALU pipe) ----
template <int CTRL, int RM = 0xF>
__device__ __forceinline__ float dppf(float x) {
    return __int_as_float(
        __builtin_amdgcn_update_dpp(0, __float_as_int(x), CTRL, RM, 0xF, true));
}
template <int CTRL>
__device__ __forceinline__ int dppi(int x) {
    return __builtin_amdgcn_update_dpp(0, x, CTRL, 0xF, 0xF, true);
}
__device__ __forceinline__ float bcast63(float x) {
    return __int_as_float(__builtin_amdgcn_readlane(__float_as_int(x), 63));
}
// full-wave sum of non-negative values, result broadcast
__device__ __forceinline__ float wsum(float x) {
    x += dppf<0x111>(x);          // row_shr:1
    x += dppf<0x112>(x);          // row_shr:2
    x += dppf<0x114>(x);          // row_shr:4
    x += dppf<0x118>(x);          // row_shr:8
    x += dppf<0x142, 0xA>(x);     // row_bcast:15 -> rows 1,3
    x += dppf<0x143, 0xC>(x);     // row_bcast:31 -> rows 2,3
    return bcast63(x);
}
__device__ __forceinline__ float shup1(float x) { return dppf<0x138>(x); } // lane i <- i-1, 0 into lane 0
__device__ __forceinline__ float shdn1(float x) { return dppf<0x130>(x); } // lane i <- i+1, 0 into lane 63
__device__ __forceinline__ float exp2i(int d) {  // 2^d, clamped to fp32-normal range
    d = d < -126 ? -126 : (d > 126 ? 126 : d);
    return __int_as_float((d + 127) << 23);
}

// ---- load one 8-row group of logits ----
template <bool FWD>
__device__ __forceinline__ void prod_load(const float2* __restrict__ rp2, float2* q,
                                          int g, int lane) {
#pragma unroll
    for (int j = 0; j < Gg; ++j) {
        int k = g * Gg + j;
        int t = FWD ? k : (Tt - 1 - k);
        q[j] = (lane < 48) ? rp2[(size_t)t * 48 + lane] : make_float2(-1e4f, -1e4f);
    }
}

// ---- in-wave softmax + gather for one 8-row group (verified arithmetic) ----
__device__ __forceinline__ void softmax_group(const float2* q, float* pl, float* pb,
                                              int idx_h, int bitsel) {
#pragma unroll
    for (int j = 0; j < Gg; ++j) {
        float ex = __builtin_amdgcn_exp2f(q[j].x * L2E);   // lanes>=48: exp2(-14427) = 0
        float ey = __builtin_amdgcn_exp2f(q[j].y * L2E);
        float gb = __shfl(ey, 47, 64);      // class 95 (blank) -> readlane
        float g0 = __shfl(ex, idx_h, 64);   // class 2*idx_h    -> bpermute
        float g1 = __shfl(ey, idx_h, 64);   // class 2*idx_h+1  -> bpermute
        float s  = wsum(ex + ey);
        float rZ = __builtin_amdgcn_rcpf(s);
        pl[j] = (bitsel ? g1 : g0) * rZ;
        pb[j] = gb * rZ;
    }
}

// ---- one 8-step DP group, linear space, per-lane exponent (verified) ----
template <bool FWD>
__device__ __forceinline__ void dp_group(const float* pl, const float* pb,
                                         float allow2f, float& st_e, float& st_o,
                                         int& ls, float& f, float& a2f) {
#pragma unroll
    for (int j = 0; j < Gg; ++j) {
        if (FWD) {
            float sh = shup1(st_o);                      // alpha(2i-1), lane i-1 scale
            float t0 = st_e + st_o;
            float ne = fmaf(f, sh, st_e) * pb[j];
            float no = fmaf(a2f, sh, t0) * pl[j];
            st_e = ne; st_o = no;
        } else {
            float en = shdn1(st_e);                      // beta(2i+2)
            float on = shdn1(st_o);                      // beta(2i+3)
            float ne = (st_e + st_o) * pb[j];
            float no = fmaf(a2f, on, fmaf(f, en, st_o)) * pl[j];
            st_e = ne; st_o = no;
        }
    }
    // per-lane exact power-of-2 rescale
    float m = fmaxf(st_e, st_o);
    bool z  = (m == 0.0f);
    int eb  = (__float_as_int(m) >> 23) & 0xFF;
    eb = eb > 253 ? 253 : eb;
    float r = z ? 1.0f : __int_as_float((254 - eb) << 23);   // 2^(127-eb), exact
    st_e *= r; st_o *= r;
    ls += z ? 0 : (eb - 127);
    // exponent adoption for zero lanes (front moves <= 8 lanes/group)
#pragma unroll
    for (int it = 0; it < 8; ++it) {
        int lsn = FWD ? dppi<0x138>(ls) : dppi<0x130>(ls);
        ls = z ? lsn : ls;
    }
    int lsn2 = FWD ? dppi<0x138>(ls) : dppi<0x130>(ls);
    f   = exp2i(lsn2 - ls);
    a2f = allow2f * f;
}

// ---- self-contained half-problem: 24 groups, software-pipelined, no barriers ----
template <bool FWD>
__device__ __forceinline__ void run_half(const float2* __restrict__ rp2, int lane,
                                         int idx_h, int bitsel, float allow2f,
                                         float& st_e, float& st_o, int& ls,
                                         float& f, float& a2f) {
    float2 q0[Gg], q1[Gg];
    float plA[Gg], pbA[Gg], plB[Gg], pbB[Gg];
    prod_load<FWD>(rp2, q0, 0, lane);
    prod_load<FWD>(rp2, q1, 1, lane);
    softmax_group(q0, plA, pbA, idx_h, bitsel);          // group 0
    for (int g2 = 0; g2 < NG / 2; ++g2) {                // 12 iterations, 2 groups each
        bool more = (g2 < NG / 2 - 1);
        if (more) prod_load<FWD>(rp2, q0, 2 * g2 + 2, lane);
        softmax_group(q1, plB, pbB, idx_h, bitsel);      // group 2*g2+1 (fills DP stalls)
        dp_group<FWD>(plA, pbA, allow2f, st_e, st_o, ls, f, a2f);   // group 2*g2
        if (more) prod_load<FWD>(rp2, q1, 2 * g2 + 3, lane);
        if (more) softmax_group(q0, plA, pbA, idx_h, bitsel);       // group 2*g2+2
        dp_group<FWD>(plB, pbB, allow2f, st_e, st_o, ls, f, a2f);   // group 2*g2+1
    }
}

// 2 waves/block: wv0 = fwd half (t=0..191), wv1 = bwd half (t=383..192). No main-loop
// barriers; one barrier to combine at t=192. Per-example NLL -> ws[b] (no atomics).
__global__ __launch_bounds__(128) void ctc_fb(const int* __restrict__ labels,
                                              const float* __restrict__ pred,
                                              float* __restrict__ nll) {
    const int b    = blockIdx.x;
    const int lane = threadIdx.x & 63;
    const int wv   = threadIdx.x >> 6;
    const float2* rp2 = (const float2*)(pred + (size_t)b * Tt * Cc);

    __shared__ float sbe[64], sbo[64];
    __shared__ int   slsb[64];

    // lane i holds label i
    int v = (lane < Ll) ? labels[(size_t)b * Ll + lane] : -1;
    int present = (lane < Ll) && (v != -1);
    int labv = (v < 0) ? 0 : v;
    unsigned long long pm = __ballot(present);
    int len = __popcll(pm);
    int idx_h  = labv >> 1;
    int bitsel = labv & 1;
    int lab_p = __shfl(labv, (lane - 1) & 63, 64);
    int lab_n = __shfl(labv, (lane + 1) & 63, 64);

    float st_e, st_o = 0.0f, f = 1.0f, a2f, allow2f;
    int   ls = 0;

    if (wv == 0) {            // fwd DP: virtual pre-start state at lane 0
        allow2f = (lane >= 1 && labv != lab_p) ? 1.0f : 0.0f;
        st_e = (lane == 0) ? 1.0f : 0.0f;
        a2f = allow2f;
        run_half<true>(rp2, lane, idx_h, bitsel, allow2f, st_e, st_o, ls, f, a2f);
    } else {                  // bwd DP: virtual post-end state at lane == len
        allow2f = (labv != lab_n) ? 1.0f : 0.0f;
        st_e = (lane == len) ? 1.0f : 0.0f;
        a2f = allow2f;
        run_half<false>(rp2, lane, idx_h, bitsel, allow2f, st_e, st_o, ls, f, a2f);
        sbe[lane]  = st_e;
        sbo[lane]  = st_o;
        slsb[lane] = ls;
    }
    __syncthreads();

    if (wv == 0) {
        // transition half-step (no emission) to meet beta at t = 192
        float sh  = shup1(st_o);
        int   lsu = dppi<0x138>(ls);
        float fup = exp2i(lsu - ls);
        float Ae = fmaf(fup, sh, st_e);
        float Ao = fmaf(allow2f * fup, sh, st_e + st_o);
        // combine in log2 domain with integer exponents restored
        float be = sbe[lane], bo = sbo[lane];
        float base = (float)(ls + slsb[lane]);
        float l1 = (Ae > 0.0f && be > 0.0f) ? __log2f(Ae) + __log2f(be) + base : LNEG;
        float l2 = (Ao > 0.0f && bo > 0.0f) ? __log2f(Ao) + __log2f(bo) + base : LNEG;
        float mm = fmaxf(l1, l2);
#pragma unroll
        for (int off = 32; off >= 1; off >>= 1) mm = fmaxf(mm, __shfl_xor(mm, off, 64));
        float ss = exp2f(l1 - mm) + exp2f(l2 - mm);
#pragma unroll
        for (int off = 32; off >= 1; off >>= 1) ss += __shfl_xor(ss, off, 64);
        if (lane == 0) {
            float ll = (mm + __log2f(ss)) * LN2;
            nll[b] = -ll;                 // plain store, no contended atomic
        }
    }
}

// ---- mean of 1024 per-example NLLs, fixed-order f64, single block ----
__global__ __launch_bounds__(256) void ctc_mean(const float* __restrict__ nll,
                                                float* __restrict__ out, float invB) {
    __shared__ double part[256];
    double s = 0.0;
#pragma unroll
    for (int i = 0; i < 4; ++i) s += (double)nll[threadIdx.x + 256 * i];
    part[threadIdx.x] = s;
    __syncthreads();
#pragma unroll
    for (int w = 128; w >= 1; w >>= 1) {
        if (threadIdx.x < w) part[threadIdx.x] += part[threadIdx.x + w];
        __syncthreads();
    }
    if (threadIdx.x == 0) out[0] = (float)(part[0] * (double)invB);
}

extern "C" void kernel_launch(void* const* d_in, const int* in_sizes, int n_in,
                              void* d_out, int out_size, void* d_ws, size_t ws_size,
                              hipStream_t stream) {
    const int*   labels = (const int*)d_in[0];
    const float* pred   = (const float*)d_in[1];
    float*       out    = (float*)d_out;
    float*       nll    = (float*)d_ws;    // 1024 floats = 4 KB

    const int B = in_sizes[0] / Ll;  // 1024

    hipLaunchKernelGGL(ctc_fb, dim3(B), dim3(128), 0, stream, labels, pred, nll);
    hipLaunchKernelGGL(ctc_mean, dim3(1), dim3(256), 0, stream, nll, out, 1.0f / (float)B);
}